// Round 11
// baseline (819.723 us; speedup 1.0000x reference)
//
#include <hip/hip_runtime.h>
#include <math.h>

// Problem constants
#define B_   64
#define N_   576
#define D_   768
#define L_   64
#define H_   8
#define HD_  96
#define NB_  (B_*N_)    // 36864 rows
#define ML_  (B_*L_)    // 4096 rows
#define KV_STRIDE_ 1536
#define SCALE_ 0.10206207f          // 96^-0.5
#define INV_SQRT_D_ 0.03608439182f  // 1/sqrt(768)
#define LO_SCALE_ 4.8828125e-4f     // 2^-11

typedef __attribute__((ext_vector_type(8))) _Float16 half8v;    // 8 fp16 (4 VGPRs)
typedef __attribute__((ext_vector_type(4))) float floatx4;      // MFMA C/D

__device__ __forceinline__ unsigned short f2h(float f) {
  _Float16 h = (_Float16)f;
  unsigned short u; __builtin_memcpy(&u, &h, 2);
  return u;
}
__device__ __forceinline__ float h2f(unsigned short u) {
  _Float16 h; __builtin_memcpy(&h, &u, 2);
  return (float)h;
}
// async global->LDS, 16B/lane: HW writes lds_base + lane*16 (wave-uniform base),
// global source is per-lane.
__device__ __forceinline__ void gload_lds16(const void* g, void* l) {
  __builtin_amdgcn_global_load_lds(
      (const __attribute__((address_space(1))) unsigned*)g,
      (__attribute__((address_space(3))) unsigned*)l, 16, 0, 0);
}

// ---------------------------------------------------------------------------
// K1: LayerNorm1 -> fp16 hi/lo split planes + token_score + row sum-of-squares
// ---------------------------------------------------------------------------
__global__ __launch_bounds__(256) void k_ln1(const float* __restrict__ x,
    const float* __restrict__ g, const float* __restrict__ bt,
    const float* __restrict__ sw, const float* __restrict__ sb,
    unsigned short* __restrict__ xh, unsigned short* __restrict__ xl,
    float* __restrict__ ts, float* __restrict__ sq)
{
  int row = blockIdx.x, tid = threadIdx.x;
  const float* xr = x + (size_t)row * D_;
  float v0 = xr[tid], v1 = xr[tid + 256], v2 = xr[tid + 512];
  __shared__ float r1[256], r2[256];
  r1[tid] = v0 + v1 + v2;
  r2[tid] = v0 * v0 + v1 * v1 + v2 * v2;
  __syncthreads();
  for (int o = 128; o > 0; o >>= 1) {
    if (tid < o) { r1[tid] += r1[tid + o]; r2[tid] += r2[tid + o]; }
    __syncthreads();
  }
  float mean = r1[0] * (1.0f / D_);
  float var  = r2[0] * (1.0f / D_) - mean * mean;
  float rstd = rsqrtf(var + 1e-5f);
  __syncthreads();
  float o0 = (v0 - mean) * rstd * g[tid      ] + bt[tid      ];
  float o1 = (v1 - mean) * rstd * g[tid + 256] + bt[tid + 256];
  float o2 = (v2 - mean) * rstd * g[tid + 512] + bt[tid + 512];
  auto split = [](float o, unsigned short& hu, unsigned short& lu) {
    _Float16 h = (_Float16)o;
    float hf = (float)h;
    _Float16 l = (_Float16)((o - hf) * 2048.0f);
    __builtin_memcpy(&hu, &h, 2);
    __builtin_memcpy(&lu, &l, 2);
  };
  unsigned short h0, l0, h1, l1, h2, l2;
  split(o0, h0, l0); split(o1, h1, l1); split(o2, h2, l2);
  unsigned short* xho = xh + (size_t)row * D_;
  unsigned short* xlo = xl + (size_t)row * D_;
  xho[tid] = h0; xho[tid + 256] = h1; xho[tid + 512] = h2;
  xlo[tid] = l0; xlo[tid + 256] = l1; xlo[tid + 512] = l2;
  r1[tid] = o0 * sw[tid] + o1 * sw[tid + 256] + o2 * sw[tid + 512];
  r2[tid] = o0 * o0 + o1 * o1 + o2 * o2;
  __syncthreads();
  for (int o = 128; o > 0; o >>= 1) {
    if (tid < o) { r1[tid] += r1[tid + o]; r2[tid] += r2[tid + o]; }
    __syncthreads();
  }
  if (tid == 0) { ts[row] = r1[0] + sb[0]; sq[row] = r2[0]; }
}

// ---------------------------------------------------------------------------
// K2: pairwise distances via fp16x2 split-precision MFMA Gram.
// gload_lds staging + XOR involution + BK=64 + XCD batch-affinity swizzle.
// ---------------------------------------------------------------------------
__global__ __launch_bounds__(256) void k_dmg(const unsigned short* __restrict__ xh,
    const unsigned short* __restrict__ xl, const float* __restrict__ sq,
    float* __restrict__ dm, float* __restrict__ dmax)
{
  __shared__ __align__(16) unsigned short S[4][96 * 64];   // 4 x 12KB = 48KB
  int flat = blockIdx.x;
  int xcd = flat & 7, seq = flat >> 3;
  int b = (seq / 21) * 8 + xcd;
  int t = seq % 21;
  int ti = 0, rl = 6;
  while (t >= rl) { t -= rl; ++ti; --rl; }
  int tj = ti + t;
  int tid = threadIdx.x;
  int wave = tid >> 6, lane = tid & 63;
  int wr = (wave >> 1) * 48, wc = (wave & 1) * 48;
  int mloc = lane & 15, quad = lane >> 4;
  size_t rowA = (size_t)b * N_ + ti * 96;
  size_t rowB = (size_t)b * N_ + tj * 96;

  const unsigned short* srcbase =
      (wave == 0) ? xh + rowA * D_ :
      (wave == 1) ? xl + rowA * D_ :
      (wave == 2) ? xh + rowB * D_ : xl + rowB * D_;
  int lrow = lane >> 3, lchunk = lane & 7;
  const unsigned short* gsrc0 = srcbase + (size_t)lrow * D_ + ((lchunk ^ lrow) * 8);
  unsigned short* lbase = &S[wave][0];

  floatx4 a1[3][3], a2[3][3];
#pragma unroll
  for (int i = 0; i < 3; ++i)
#pragma unroll
    for (int j = 0; j < 3; ++j) {
      a1[i][j] = (floatx4){0.f, 0.f, 0.f, 0.f};
      a2[i][j] = (floatx4){0.f, 0.f, 0.f, 0.f};
    }

  for (int kt = 0; kt < D_; kt += 64) {
    __syncthreads();
#pragma unroll
    for (int rb = 0; rb < 12; ++rb)
      gload_lds16(gsrc0 + (size_t)rb * 8 * D_ + kt, lbase + rb * 8 * 64);
    __syncthreads();
#pragma unroll
    for (int ks = 0; ks < 2; ++ks) {
      half8v ah[3], al[3], bh[3], bl[3];
      int cperm = (((ks << 2) | quad) ^ (mloc & 7)) * 8;
#pragma unroll
      for (int i = 0; i < 3; ++i) {
        int ro = (wr + i * 16 + mloc) * 64 + cperm;
        ah[i] = *(const half8v*)&S[0][ro];
        al[i] = *(const half8v*)&S[1][ro];
      }
#pragma unroll
      for (int j = 0; j < 3; ++j) {
        int ro = (wc + j * 16 + mloc) * 64 + cperm;
        bh[j] = *(const half8v*)&S[2][ro];
        bl[j] = *(const half8v*)&S[3][ro];
      }
#pragma unroll
      for (int i = 0; i < 3; ++i)
#pragma unroll
        for (int j = 0; j < 3; ++j) {
          a1[i][j] = __builtin_amdgcn_mfma_f32_16x16x32_f16(ah[i], bh[j], a1[i][j], 0, 0, 0);
          a2[i][j] = __builtin_amdgcn_mfma_f32_16x16x32_f16(ah[i], bl[j], a2[i][j], 0, 0, 0);
          a2[i][j] = __builtin_amdgcn_mfma_f32_16x16x32_f16(al[i], bh[j], a2[i][j], 0, 0, 0);
        }
    }
  }

  const float* sqb = sq + b * N_;
  float* dmb = dm + (size_t)b * N_ * N_;
  bool diag = (ti == tj);
  float vmax = 0.f;
#pragma unroll
  for (int j = 0; j < 3; ++j) {
    int gj = tj * 96 + wc + j * 16 + mloc;
    float sj = sqb[gj];
#pragma unroll
    for (int i = 0; i < 3; ++i) {
      int gi0 = ti * 96 + wr + i * 16 + quad * 4;
#pragma unroll
      for (int reg = 0; reg < 4; ++reg) {
        int gi = gi0 + reg;
        float g = a1[i][j][reg] + a2[i][j][reg] * LO_SCALE_;
        float d = sqb[gi] + sj - 2.0f * g;
        float v = sqrtf(fmaxf(d, 0.0f)) * INV_SQRT_D_;
        vmax = fmaxf(vmax, v);
        if (!diag || gj >= gi) {
          dmb[(size_t)gi * N_ + gj] = v;
          dmb[(size_t)gj * N_ + gi] = v;
        }
      }
    }
  }
#pragma unroll
  for (int msk = 32; msk >= 1; msk >>= 1) vmax = fmaxf(vmax, __shfl_xor(vmax, msk));
  if (lane == 0) atomicMax((unsigned int*)(dmax + b), __float_as_uint(vmax));
}

// ---------------------------------------------------------------------------
// K3: kNN density — 4 rows/block (wave per row), float4 dm reads.
// min-5 selection is order-independent -> bit-identical density.
// ---------------------------------------------------------------------------
__global__ __launch_bounds__(256) void k_density(const float* __restrict__ dm,
    const float* __restrict__ noise, float* __restrict__ den)
{
  int row = blockIdx.x * 4 + (threadIdx.x >> 6);
  int lane = threadIdx.x & 63;
  const float* r = dm + (size_t)row * N_;
  float a0 = 1e30f, a1 = 1e30f, a2 = 1e30f, a3 = 1e30f, a4 = 1e30f;
  auto ins5 = [&](float xv) {
    a4 = fminf(a4, xv);
    float t;
    t = fminf(a3, a4); a4 = fmaxf(a3, a4); a3 = t;
    t = fminf(a2, a3); a3 = fmaxf(a2, a3); a2 = t;
    t = fminf(a1, a2); a2 = fmaxf(a1, a2); a1 = t;
    t = fminf(a0, a1); a1 = fmaxf(a0, a1); a0 = t;
  };
  float4 v0 = *(const float4*)(r + lane * 4);
  float4 v1 = *(const float4*)(r + (lane + 64) * 4);
  ins5(v0.x); ins5(v0.y); ins5(v0.z); ins5(v0.w);
  ins5(v1.x); ins5(v1.y); ins5(v1.z); ins5(v1.w);
  if (lane < 16) {
    float4 v2 = *(const float4*)(r + (lane + 128) * 4);
    ins5(v2.x); ins5(v2.y); ins5(v2.z); ins5(v2.w);
  }
  for (int m = 1; m < 64; m <<= 1) {
    float b0 = __shfl_xor(a0, m), b1 = __shfl_xor(a1, m), b2 = __shfl_xor(a2, m);
    float b3 = __shfl_xor(a3, m), b4 = __shfl_xor(a4, m);
    ins5(b0); ins5(b1); ins5(b2); ins5(b3); ins5(b4);
  }
  if (lane == 0) {
    float ms = (a0 * a0 + a1 * a1 + a2 * a2 + a3 * a3 + a4 * a4) * 0.2f;
    den[row] = expf(-ms) + noise[row] * 1e-6f;
  }
}

// ---------------------------------------------------------------------------
// K5: dist-to-higher-density + score — 4 rows/block, float4 reads.
// fmin reduction is order-independent -> bit-identical score.
// ---------------------------------------------------------------------------
__global__ __launch_bounds__(256) void k_dist(const float* __restrict__ dm,
    const float* __restrict__ den, const float* __restrict__ dmax,
    float* __restrict__ score)
{
  int row = blockIdx.x * 4 + (threadIdx.x >> 6);
  int lane = threadIdx.x & 63;
  int b = row / N_;
  float di = den[row], dx = dmax[b];
  const float* r = dm + (size_t)row * N_;
  const float* db = den + b * N_;
  float m = dx;
  auto proc4 = [&](int f4) {
    float4 rv = *(const float4*)(r + f4 * 4);
    float4 dv = *(const float4*)(db + f4 * 4);
    m = fminf(m, (dv.x > di) ? rv.x : dx);
    m = fminf(m, (dv.y > di) ? rv.y : dx);
    m = fminf(m, (dv.z > di) ? rv.z : dx);
    m = fminf(m, (dv.w > di) ? rv.w : dx);
  };
  proc4(lane); proc4(lane + 64);
  if (lane < 16) proc4(lane + 128);
  for (int msk = 1; msk < 64; msk <<= 1) m = fminf(m, __shfl_xor(m, msk));
  if (lane == 0) score[row] = m * di;
}

// ---------------------------------------------------------------------------
// K6: fused cluster selection: bitonic top-64 (same compare network as before,
// tid<512 one pair each) + nearest-center assign + center override + stable
// counting-sort bucket. One 576-thread block per batch. Outputs ord/starts.
// ---------------------------------------------------------------------------
__global__ __launch_bounds__(576) void k_cluster(const float* __restrict__ score,
    const float* __restrict__ dm, int* __restrict__ ord, int* __restrict__ starts)
{
  int b = blockIdx.x, tid = threadIdx.x;
  __shared__ float s[1024];
  __shared__ int   si[1024];
  __shared__ int   ctr[L_];
  __shared__ int   icS[N_];
  for (int i = tid; i < 1024; i += 576) {
    s[i] = (i < N_) ? score[b * N_ + i] : -3.0e38f;
    si[i] = i;
  }
  __syncthreads();
  for (int k = 2; k <= 1024; k <<= 1) {
    for (int j = k >> 1; j > 0; j >>= 1) {
      if (tid < 512) {
        int lo = tid & (j - 1);
        int i = ((tid ^ lo) << 1) | lo;
        int p = i | j;
        float as = s[i], bs = s[p];
        int ai = si[i], bi = si[p];
        bool bba = (bs > as) || (bs == as && bi < ai);
        bool up = ((i & k) == 0);
        bool dosw = up ? bba : !bba;
        if (dosw) { s[i] = bs; s[p] = as; si[i] = bi; si[p] = ai; }
      }
      __syncthreads();
    }
  }
  if (tid < L_) ctr[tid] = si[tid];
  __syncthreads();
  // assign
  {
    int n = tid;
    const float* dmb = dm + (size_t)b * N_ * N_;
    float best = 1e30f; int bl = 0;
    for (int l = 0; l < L_; ++l) {
      float v = dmb[(size_t)ctr[l] * N_ + n];
      if (v < best) { best = v; bl = l; }
    }
    for (int l = 0; l < L_; ++l)
      if (ctr[l] == n) bl = l;
    icS[n] = bl;
  }
  __syncthreads();
  // bucket (first wave, one thread per cluster)
  if (tid < L_) {
    int l = tid;
    int cnt = 0;
    for (int nn = 0; nn < N_; ++nn) cnt += (icS[nn] == l) ? 1 : 0;
    int inc = cnt;
    for (int d = 1; d < 64; d <<= 1) {
      int v = __shfl_up(inc, d);
      if (l >= d) inc += v;
    }
    int excl = inc - cnt;
    if (l == 0) starts[b * 65] = 0;
    starts[b * 65 + l + 1] = inc;
    int p = excl;
    for (int nn = 0; nn < N_; ++nn)
      if (icS[nn] == l) ord[b * N_ + p++] = nn;
  }
}

// ---------------------------------------------------------------------------
// K8: merger (gather via inverted index) — bit-identical to scan version.
// ---------------------------------------------------------------------------
__global__ __launch_bounds__(256) void k_merge(const unsigned short* __restrict__ xh,
    const unsigned short* __restrict__ xl,
    const float* __restrict__ ts, const int* __restrict__ ord,
    const int* __restrict__ starts, float* __restrict__ qin)
{
  int blk = blockIdx.x;
  int b = blk >> 6, l = blk & 63;
  int tid = threadIdx.x;
  int s0 = starts[b * 65 + l], s1 = starts[b * 65 + l + 1];
  const float* tsb = ts + b * N_;
  const int* ob = ord + b * N_;
  const unsigned short* xhb = xh + (size_t)b * N_ * D_;
  const unsigned short* xlb = xl + (size_t)b * N_ * D_;
  float a0 = 0.f, a1 = 0.f, a2 = 0.f, wsum = 0.f;
  for (int k = s0; k < s1; ++k) {
    int n = ob[k];
    float w = expf(tsb[n]);
    wsum += w;
    const unsigned short* hr = xhb + (size_t)n * D_;
    const unsigned short* lr = xlb + (size_t)n * D_;
    float x0 = h2f(hr[tid      ]) + h2f(lr[tid      ]) * LO_SCALE_;
    float x1 = h2f(hr[tid + 256]) + h2f(lr[tid + 256]) * LO_SCALE_;
    float x2 = h2f(hr[tid + 512]) + h2f(lr[tid + 512]) * LO_SCALE_;
    a0 += w * x0; a1 += w * x1; a2 += w * x2;
  }
  float inv = 1.0f / (wsum + 1e-6f);
  float* q = qin + (size_t)blk * D_;
  q[tid] = a0 * inv; q[tid + 256] = a1 * inv; q[tid + 512] = a2 * inv;
}

// ---------------------------------------------------------------------------
// Weight transposes, all six in one launch. flat grid 6912:
//   [0,2304): four 768x768 (wq,wk,wv,pw) — 576 tiles each
//   [2304,4608): f1w 768x3072 (24x96 tiles)
//   [4608,6912): f2w 3072x768 (96x24 tiles)
// ---------------------------------------------------------------------------
__global__ __launch_bounds__(256) void k_wt6(
    const float* __restrict__ wq, const float* __restrict__ wk,
    const float* __restrict__ wv, const float* __restrict__ pw,
    const float* __restrict__ f1w, const float* __restrict__ f2w,
    unsigned short* __restrict__ WTQ, unsigned short* __restrict__ WTKV,
    unsigned short* __restrict__ WTP, unsigned short* __restrict__ WT1,
    unsigned short* __restrict__ WT2)
{
  __shared__ float t[32][33];
  int flat = blockIdx.x;
  const float* W; unsigned short* WT; int K, N, kx, ny;
  if (flat < 2304) {
    int wi = flat / 576, tt = flat % 576;
    K = D_; N = D_; kx = tt % 24; ny = tt / 24;
    W  = (wi == 0) ? wq : (wi == 1) ? wk : (wi == 2) ? wv : pw;
    WT = (wi == 0) ? WTQ : (wi == 1) ? WTKV
       : (wi == 2) ? (WTKV + (size_t)D_ * D_) : WTP;
  } else if (flat < 4608) {
    int tt = flat - 2304; K = D_; N = 4 * D_; kx = tt % 24; ny = tt / 24;
    W = f1w; WT = WT1;
  } else {
    int tt = flat - 4608; K = 4 * D_; N = D_; kx = tt % 96; ny = tt / 96;
    W = f2w; WT = WT2;
  }
  int k0 = kx * 32, n0 = ny * 32;
  int tid = threadIdx.x;
  int r = tid >> 3, c4 = (tid & 7) * 4;
  float4 v = *(const float4*)(W + (size_t)(k0 + r) * N + n0 + c4);
  t[r][c4] = v.x; t[r][c4 + 1] = v.y; t[r][c4 + 2] = v.z; t[r][c4 + 3] = v.w;
  __syncthreads();
  ushort4 s4;
  s4.x = f2h(t[c4 + 0][r]); s4.y = f2h(t[c4 + 1][r]);
  s4.z = f2h(t[c4 + 2][r]); s4.w = f2h(t[c4 + 3][r]);
  *(ushort4*)(WT + (size_t)(n0 + r) * K + k0 + c4) = s4;
}

// ---------------------------------------------------------------------------
// MFMA GEMM: C[M,N] = epilogue(A[M,K] @ WT[N,K]^T), fp16 MFMA, fp32 accum.
// BK=64; As/Bs [128][64] with XOR-chunk swizzle; gload_lds staging.
// XCD M-panel affinity swizzle (T1). Bit-identical outputs.
// ---------------------------------------------------------------------------
template<int EPI, int ASRC>
__global__ __launch_bounds__(256) void k_mgemm(const void* __restrict__ Ap_,
    const unsigned short* __restrict__ Wt, const float* __restrict__ bias,
    const float* __restrict__ res, void* __restrict__ outp,
    int M, int Nd, int Kd)
{
  __shared__ __align__(16) unsigned short As[128 * 64];
  __shared__ __align__(16) unsigned short Bs[128 * 64];
  int tid = threadIdx.x;
  int gn = Nd >> 7;
  int flat = blockIdx.x;
  int xcd = flat & 7, seq = flat >> 3;
  int bmg = seq / gn, bnn = seq - bmg * gn;
  int bm = (bmg * 8 + xcd) * 128, bn = bnn * 128;
  int wave = tid >> 6, lane = tid & 63;
  int wr = (wave >> 1) * 64, wc = (wave & 1) * 64;
  int mloc = lane & 15, quad = lane >> 4;

  floatx4 acc[4][4];
#pragma unroll
  for (int i = 0; i < 4; ++i)
#pragma unroll
    for (int j = 0; j < 4; ++j)
      acc[i][j] = (floatx4){0.f, 0.f, 0.f, 0.f};

  int lrow = lane >> 3, lchunk = lane & 7;
  const unsigned short* bsrc0 =
      Wt + (size_t)(bn + wave * 32 + lrow) * Kd + ((lchunk ^ lrow) * 8);
  unsigned short* bdst0 = &Bs[(wave * 32) * 64];
  const unsigned short* asrc0 = (ASRC == 1)
      ? (const unsigned short*)Ap_ + (size_t)(bm + wave * 32 + lrow) * Kd + ((lchunk ^ lrow) * 8)
      : nullptr;
  unsigned short* adst0 = &As[(wave * 32) * 64];

  for (int kt = 0; kt < Kd; kt += 64) {
    __syncthreads();
#pragma unroll
    for (int rb = 0; rb < 4; ++rb)
      gload_lds16(bsrc0 + (size_t)rb * 8 * Kd + kt, bdst0 + rb * 8 * 64);
    if (ASRC == 1) {
#pragma unroll
      for (int rb = 0; rb < 4; ++rb)
        gload_lds16(asrc0 + (size_t)rb * 8 * Kd + kt, adst0 + rb * 8 * 64);
    } else {
      const float* A = (const float*)Ap_;
#pragma unroll
      for (int it = 0; it < 4; ++it) {
        int idx = tid + it * 256;
        int r = idx >> 3, c = idx & 7;
        const float* ap = A + (size_t)(bm + r) * Kd + kt + c * 8;
        float4 f0 = *(const float4*)ap;
        float4 f1 = *(const float4*)(ap + 4);
        uint4 pk;
        pk.x = (unsigned)f2h(f0.x) | ((unsigned)f2h(f0.y) << 16);
        pk.y = (unsigned)f2h(f0.z) | ((unsigned)f2h(f0.w) << 16);
        pk.z = (unsigned)f2h(f1.x) | ((unsigned)f2h(f1.y) << 16);
        pk.w = (unsigned)f2h(f1.z) | ((unsigned)f2h(f1.w) << 16);
        *(uint4*)&As[r * 64 + ((c ^ (r & 7)) * 8)] = pk;
      }
    }
    __syncthreads();
#pragma unroll
    for (int ks = 0; ks < 2; ++ks) {
      half8v af[4], bf[4];
      int cperm = (((ks << 2) | quad) ^ (mloc & 7)) * 8;
#pragma unroll
      for (int i = 0; i < 4; ++i)
        af[i] = *(const half8v*)&As[(wr + i * 16 + mloc) * 64 + cperm];
#pragma unroll
      for (int j = 0; j < 4; ++j)
        bf[j] = *(const half8v*)&Bs[(wc + j * 16 + mloc) * 64 + cperm];
#pragma unroll
      for (int i = 0; i < 4; ++i)
#pragma unroll
        for (int j = 0; j < 4; ++j)
          acc[i][j] = __builtin_amdgcn_mfma_f32_16x16x32_f16(af[i], bf[j], acc[i][j], 0, 0, 0);
    }
  }

  float bv[4] = {0.f, 0.f, 0.f, 0.f};
  if (EPI >= 1) {
#pragma unroll
    for (int j = 0; j < 4; ++j) bv[j] = bias[bn + wc + j * 16 + mloc];
  }
#pragma unroll
  for (int i = 0; i < 4; ++i) {
    int gr0 = bm + wr + i * 16 + quad * 4;
#pragma unroll
    for (int j = 0; j < 4; ++j) {
      int gcn = bn + wc + j * 16 + mloc;
#pragma unroll
      for (int reg = 0; reg < 4; ++reg) {
        float v = acc[i][j][reg];
        size_t off = (size_t)(gr0 + reg) * Nd + gcn;
        if (EPI == 0) {
          ((unsigned short*)outp)[off] = f2h(v);
        } else if (EPI == 1) {
          ((float*)outp)[off] = v + bv[j] + res[off];
        } else {
          v += bv[j];
          v = 0.5f * v * (1.0f + erff(v * 0.70710678f));
          ((unsigned short*)outp)[off] = f2h(v);
        }
      }
    }
  }
}

// ---------------------------------------------------------------------------
// K12: MFMA flash cross-attention with token-score bias (all fp16 operands).
// ---------------------------------------------------------------------------
__global__ __launch_bounds__(256) void k_attn(const unsigned short* __restrict__ Qu,
    const unsigned short* __restrict__ KVu, const float* __restrict__ ts,
    float* __restrict__ aout)
{
  __shared__ __align__(16) unsigned short Ks[64 * 104];
  __shared__ __align__(16) unsigned short VsT[96 * 64];
  __shared__ __align__(16) unsigned short sPa[64 * 64];
  __shared__ float tsb[64];
  int h = blockIdx.x, b = blockIdx.y;
  int tid = threadIdx.x;
  int wave = tid >> 6, lane = tid & 63;
  int mloc = lane & 15, quad = lane >> 4;

  half8v qf[3];
  {
    const unsigned short* qrow = Qu + (size_t)(b * 64 + wave * 16 + mloc) * D_ + h * 96 + quad * 8;
#pragma unroll
    for (int k = 0; k < 3; ++k) qf[k] = *(const half8v*)(qrow + k * 32);
  }

  floatx4 of[6];
#pragma unroll
  for (int dt = 0; dt < 6; ++dt) of[dt] = (floatx4){0.f, 0.f, 0.f, 0.f};
  float m[4], l[4];
#pragma unroll
  for (int r = 0; r < 4; ++r) { m[r] = -1e30f; l[r] = 0.f; }

  for (int jt = 0; jt < 9; ++jt) {
    int j0 = jt * 64;
    __syncthreads();
#pragma unroll
    for (int t = 0; t < 3; ++t) {
      int id = tid + t * 256;
      int row = id / 12, c = id % 12;
      *(uint4*)&Ks[row * 104 + c * 8] =
          *(const uint4*)(KVu + (size_t)(b * N_ + j0 + row) * KV_STRIDE_ + h * 96 + c * 8);
    }
#pragma unroll
    for (int t = 0; t < 3; ++t) {
      int id = tid + t * 256;
      int keyp = id & 31, dq = (id >> 5) * 4;
      int key = keyp * 2;
      const unsigned short* vp =
          KVu + (size_t)(b * N_ + j0 + key) * KV_STRIDE_ + 768 + h * 96 + dq;
      ushort4 v0 = *(const ushort4*)vp;
      ushort4 v1 = *(const ushort4*)(vp + KV_STRIDE_);
      unsigned pk0 = (unsigned)v0.x | ((unsigned)v1.x << 16);
      unsigned pk1 = (unsigned)v0.y | ((unsigned)v1.y << 16);
      unsigned pk2 = (unsigned)v0.z | ((unsigned)v1.z << 16);
      unsigned pk3 = (unsigned)v0.w | ((unsigned)v1.w << 16);
      int cbase = key >> 3, off = key & 7;
#pragma unroll
      for (int i = 0; i < 4; ++i) {
        int d = dq + i;
        unsigned pv = (i == 0) ? pk0 : (i == 1) ? pk1 : (i == 2) ? pk2 : pk3;
        *(unsigned*)&VsT[d * 64 + ((cbase ^ (d & 7)) << 3) + off] = pv;
      }
    }
    if (tid < 64) tsb[tid] = ts[b * N_ + j0 + tid];
    __syncthreads();

    floatx4 acc[4];
#pragma unroll
    for (int j = 0; j < 4; ++j) acc[j] = (floatx4){0.f, 0.f, 0.f, 0.f};
#pragma unroll
    for (int j = 0; j < 4; ++j)
#pragma unroll
      for (int k = 0; k < 3; ++k) {
        half8v kf = *(const half8v*)&Ks[(j * 16 + mloc) * 104 + k * 32 + quad * 8];
        acc[j] = __builtin_amdgcn_mfma_f32_16x16x32_f16(qf[k], kf, acc[j], 0, 0, 0);
      }

    float ts4[4];
#pragma unroll
    for (int j = 0; j < 4; ++j) ts4[j] = tsb[j * 16 + mloc];
    float rm[4] = {-1e30f, -1e30f, -1e30f, -1e30f};
#pragma unroll
    for (int j = 0; j < 4; ++j)
#pragma unroll
      for (int r = 0; r < 4; ++r) {
        acc[j][r] = acc[j][r] * SCALE_ + ts4[j];
        rm[r] = fmaxf(rm[r], acc[j][r]);
      }
#pragma unroll
    for (int r = 0; r < 4; ++r) {
      rm[r] = fmaxf(rm[r], __shfl_xor(rm[r], 1));
      rm[r] = fmaxf(rm[r], __shfl_xor(rm[r], 2));
      rm[r] = fmaxf(rm[r], __shfl_xor(rm[r], 4));
      rm[r] = fmaxf(rm[r], __shfl_xor(rm[r], 8));
    }
    float alpha[4], rs[4];
#pragma unroll
    for (int r = 0; r < 4; ++r) {
      float mn = fmaxf(m[r], rm[r]);
      alpha[r] = __expf(m[r] - mn);
      m[r] = mn;
      rs[r] = 0.f;
    }
#pragma unroll
    for (int j = 0; j < 4; ++j)
#pragma unroll
      for (int r = 0; r < 4; ++r) {
        float p = __expf(acc[j][r] - m[r]);
        acc[j][r] = p; rs[r] += p;
      }
#pragma unroll
    for (int r = 0; r < 4; ++r) {
      rs[r] += __shfl_xor(rs[r], 1); rs[r] += __shfl_xor(rs[r], 2);
      rs[r] += __shfl_xor(rs[r], 4); rs[r] += __shfl_xor(rs[r], 8);
      l[r] = l[r] * alpha[r] + rs[r];
    }
#pragma unroll
    for (int dt = 0; dt < 6; ++dt)
#pragma unroll
      for (int r = 0; r < 4; ++r) of[dt][r] *= alpha[r];

#pragma unroll
    for (int j = 0; j < 4; ++j)
#pragma unroll
      for (int r = 0; r < 4; ++r) {
        int row = wave * 16 + quad * 4 + r;
        int key = j * 16 + mloc;
        sPa[row * 64 + (((key >> 3) ^ (row & 7)) << 3) + (key & 7)] = f2h(acc[j][r]);
      }
    half8v pa[2];
    int prow = wave * 16 + mloc;
#pragma unroll
    for (int f2 = 0; f2 < 2; ++f2)
      pa[f2] = *(const half8v*)&sPa[prow * 64 + (((f2 * 4 + quad) ^ (prow & 7)) << 3)];
#pragma unroll
    for (int dt = 0; dt < 6; ++dt)
#pragma unroll
      for (int f2 = 0; f2 < 2; ++f2) {
        int vrow = dt * 16 + mloc;
        half8v vf = *(const half8v*)&VsT[vrow * 64 + (((f2 * 4 + quad) ^ (vrow & 7)) << 3)];
        of[dt] = __builtin_amdgcn_mfma_f32_16x16x32_f16(pa[f2], vf, of[dt], 0, 0, 0);
      }
  }

  float linv[4];
#pragma unroll
  for (int r = 0; r < 4; ++r) linv[r] = 1.0f / l[r];
#pragma unroll
  for (int dt = 0; dt < 6; ++dt)
#pragma unroll
    for (int r = 0; r < 4; ++r) {
      int row = b * 64 + wave * 16 + quad * 4 + r;
      int col = h * 96 + dt * 16 + mloc;
      aout[(size_t)row * D_ + col] = of[dt][r] * linv[r];
    }
}

// ---------------------------------------------------------------------------
// K14: LayerNorm2 (fp32 in -> fp32 out)
// ---------------------------------------------------------------------------
__global__ __launch_bounds__(256) void k_ln2(const float* __restrict__ f,
    const float* __restrict__ g, const float* __restrict__ bt, float* __restrict__ out)
{
  int row = blockIdx.x, tid = threadIdx.x;
  const float* fr = f + (size_t)row * D_;
  float v0 = fr[tid], v1 = fr[tid + 256], v2 = fr[tid + 512];
  __shared__ float r1[256], r2[256];
  r1[tid] = v0 + v1 + v2;
  r2[tid] = v0 * v0 + v1 * v1 + v2 * v2;
  __syncthreads();
  for (int o = 128; o > 0; o >>= 1) {
    if (tid < o) { r1[tid] += r1[tid + o]; r2[tid] += r2[tid + o]; }
    __syncthreads();
  }
  float mean = r1[0] * (1.0f / D_);
  float var  = r2[0] * (1.0f / D_) - mean * mean;
  float rstd = rsqrtf(var + 1e-5f);
  float* oo = out + (size_t)row * D_;
  oo[tid      ] = (v0 - mean) * rstd * g[tid      ] + bt[tid      ];
  oo[tid + 256] = (v1 - mean) * rstd * g[tid + 256] + bt[tid + 256];
  oo[tid + 512] = (v2 - mean) * rstd * g[tid + 512] + bt[tid + 512];
}

// ---------------------------------------------------------------------------
// Launch
// ---------------------------------------------------------------------------
extern "C" void kernel_launch(void* const* d_in, const int* in_sizes, int n_in,
                              void* d_out, int out_size, void* d_ws, size_t ws_size,
                              hipStream_t stream)
{
  (void)in_sizes; (void)n_in; (void)out_size; (void)ws_size;
  const float* x    = (const float*)d_in[0];
  const float* nois = (const float*)d_in[1];
  const float* n1g  = (const float*)d_in[2];
  const float* n1b  = (const float*)d_in[3];
  const float* sw   = (const float*)d_in[4];
  const float* sb   = (const float*)d_in[5];
  const float* wq   = (const float*)d_in[6];
  const float* wk   = (const float*)d_in[7];
  const float* wv   = (const float*)d_in[8];
  const float* pw   = (const float*)d_in[9];
  const float* pb   = (const float*)d_in[10];
  const float* n2g  = (const float*)d_in[11];
  const float* n2b  = (const float*)d_in[12];
  const float* f1w  = (const float*)d_in[13];
  const float* f1b  = (const float*)d_in[14];
  const float* f2w  = (const float*)d_in[15];
  const float* f2b  = (const float*)d_in[16];

  float* ws    = (float*)d_ws;
  unsigned short* XH = (unsigned short*)ws;                 // fp16 hi plane
  unsigned short* XL = XH + (size_t)NB_ * D_;               // fp16 lo plane
  float* RG    = ws + (size_t)NB_ * D_;
  float* QIN   = RG + (size_t)NB_ * D_;
  float* FEAT  = QIN + (size_t)ML_ * D_;
  float* AOUT  = FEAT + (size_t)ML_ * D_;
  float* QBUF  = AOUT + (size_t)ML_ * D_;
  float* P     = QBUF + (size_t)ML_ * D_;
  unsigned short* QH16 = (unsigned short*)P;  P += (size_t)ML_ * D_ / 2;
  unsigned short* WTQ  = (unsigned short*)P;  P += (size_t)D_ * D_ / 2;
  unsigned short* WTKV = (unsigned short*)P;  P += (size_t)D_ * D_;     // K then V
  unsigned short* WTP  = (unsigned short*)P;  P += (size_t)D_ * D_ / 2;
  unsigned short* WT1  = (unsigned short*)P;  P += (size_t)D_ * 4 * D_ / 2;
  unsigned short* WT2  = (unsigned short*)P;  P += (size_t)D_ * 4 * D_ / 2;
  float* TS    = P;
  float* SQ    = TS + NB_;
  float* DEN   = SQ + NB_;
  float* SCORE = DEN + NB_;
  float* DMAX  = SCORE + NB_;
  int*   IDXD  = (int*)(DMAX + 64);
  int*   IDXC  = IDXD + ML_;
  int*   ORD   = IDXC + NB_;
  int*   STARTS= ORD + NB_;           // B_*65 ints
  float* DM    = RG;                               // phase 1
  unsigned short* KVB = (unsigned short*)RG;       // phase 2: [NB_][1536] K|V
  unsigned short* HID = (unsigned short*)RG;       // phase 3

  hipMemsetAsync(DMAX, 0, 64 * sizeof(float), stream);
  k_wt6<<<6912, 256, 0, stream>>>(wq, wk, wv, pw, f1w, f2w,
                                  WTQ, WTKV, WTP, WT1, WT2);

  k_ln1<<<NB_, 256, 0, stream>>>(x, n1g, n1b, sw, sb, XH, XL, TS, SQ);
  k_dmg<<<1344, 256, 0, stream>>>(XH, XL, SQ, DM, DMAX);
  k_density<<<NB_ / 4, 256, 0, stream>>>(DM, nois, DEN);
  k_dist<<<NB_ / 4, 256, 0, stream>>>(DM, DEN, DMAX, SCORE);
  k_cluster<<<B_, 576, 0, stream>>>(SCORE, DM, ORD, STARTS);
  k_merge<<<ML_, 256, 0, stream>>>(XH, XL, TS, ORD, STARTS, QIN);

  k_mgemm<0, 0><<<(ML_ / 128) * (D_ / 128), 256, 0, stream>>>(
      QIN, WTQ, nullptr, nullptr, QH16, ML_, D_, D_);
  k_mgemm<0, 1><<<(NB_ / 128) * (KV_STRIDE_ / 128), 256, 0, stream>>>(
      XH, WTKV, nullptr, nullptr, KVB, NB_, KV_STRIDE_, D_);
  k_attn<<<dim3(H_, B_), 256, 0, stream>>>(QH16, KVB, TS, AOUT);
  k_mgemm<1, 0><<<(ML_ / 128) * (D_ / 128), 256, 0, stream>>>(
      AOUT, WTP, pb, QIN, FEAT, ML_, D_, D_);
  k_ln2<<<ML_, 256, 0, stream>>>(FEAT, n2g, n2b, QBUF);
  k_mgemm<2, 0><<<(ML_ / 128) * ((4 * D_) / 128), 256, 0, stream>>>(
      QBUF, WT1, f1b, nullptr, HID, ML_, 4 * D_, D_);
  k_mgemm<1, 1><<<(ML_ / 128) * (D_ / 128), 256, 0, stream>>>(
      HID, WT2, f2b, FEAT, d_out, ML_, D_, 4 * D_);
}